// Round 5
// baseline (627.786 us; speedup 1.0000x reference)
//
#include <hip/hip_runtime.h>
#include <cstdint>
#include <cfloat>

#define N_   32
#define D_   512
#define T_   2048
#define NC   512
#define NROW (N_ * T_)           // 65536 rows
#define OUT_ELEMS (N_ * D_ * T_) // 33554432
#define TB   64                  // t columns per block
#define THREADS 512
#define GRID 1024
#define DELTA 2e-4f

typedef __attribute__((ext_vector_type(8)))  short short8;
typedef __attribute__((ext_vector_type(16))) float f32x16;

// ws layout (4B units): [0] closs | [1] ticket | [16..527] hist | [528..1039] cbn2
// | byte 4160: cbf short8[65536] (1MB), layout [ks(32)][h(2)][ct(16)][l(64)]

__device__ inline unsigned short f2bf(float x) {
    unsigned int u = __float_as_uint(x);
    return (unsigned short)((u + 0x7fffu + ((u >> 16) & 1u)) >> 16);
}
__device__ inline float bf2f(unsigned short b) {
    return __uint_as_float(((unsigned int)b) << 16);
}

// merged: zero ws header + codebook norms + MFMA fragment build (hi/lo bf16)
__global__ __launch_bounds__(512) void prep_k(const float* __restrict__ cb,
                                              float* __restrict__ cbn2,
                                              short8* __restrict__ cbf,
                                              unsigned int* __restrict__ wsz) {
    const int tid = threadIdx.x, bid = blockIdx.x;
    if (bid == 0) {
        wsz[tid] = 0u;                      // 0..511
        if (tid < 16) wsz[512 + tid] = 0u;  // 512..527
    }
    // codebook row norms: wave w owns code c
    {
        int w = tid >> 6, l = tid & 63;
        int c = bid * 8 + w;
        const float* row = cb + (size_t)c * D_;
        float s = 0.f;
#pragma unroll
        for (int j = 0; j < 8; ++j) { float v = row[l * 8 + j]; s = fmaf(v, v, s); }
#pragma unroll
        for (int o = 32; o; o >>= 1) s += __shfl_down(s, o);
        if (l == 0) cbn2[c] = s;
    }
    // fragments for 32x32x16: lane l holds A[row=l&31][k=8*(l>>5)+j]
    {
        int gid = bid * 512 + tid;               // 0..32767
        int ks = gid >> 10, ct = (gid >> 6) & 15, fl = gid & 63;
        const float* src = cb + (size_t)(ct * 32 + (fl & 31)) * D_ + ks * 16 + 8 * (fl >> 5);
        short8 h, lo;
#pragma unroll
        for (int j = 0; j < 8; ++j) {
            float v = src[j];
            unsigned short hb = f2bf(v);
            h[j]  = (short)hb;
            lo[j] = (short)f2bf(v - bf2f(hb));
        }
        cbf[((ks * 2 + 0) * 16 + ct) * 64 + fl] = h;
        cbf[((ks * 2 + 1) * 16 + ct) * 64 + fl] = lo;
    }
}

__global__ __launch_bounds__(THREADS, 4) void vq_main(
    const float* __restrict__ x, const float* __restrict__ cb,
    float* __restrict__ out, float* __restrict__ closs,
    unsigned int* __restrict__ hist, const float* __restrict__ cbn2g,
    const short8* __restrict__ cbf, unsigned int* __restrict__ ticket) {

    __shared__ union U {
        short8 slab[2048];                  // 32KB: [h(2)][ct(16)][l(64)] for one ks
        struct {
            float ot[64][69];               // epilogue transpose (pad 69: 2-way max)
            float redv[4][64];
            int   redi[4][64];
            int   cand[64][8];
            int   qrow[64];
        } ep;
    } u;
    __shared__ float cbn2s[NC];
    __shared__ float m1s[TB];
    __shared__ int   sidx[TB], ccnt[TB];
    __shared__ int   qn, lastf;
    __shared__ unsigned int histl[NC];
    __shared__ float psum[8];

    const int tid = threadIdx.x, l = tid & 63, w = tid >> 6;
    const int q = w & 3, tg = w >> 2;       // code-quarter, t-group
    const int col = l & 31, hh = l >> 5;    // D-col (t), k-half / row-half
    const int bid = blockIdx.x;
    const int n = bid >> 5, t0 = (bid & 31) * TB;
    const int t = t0 + tg * 32 + col;
    const size_t xnb = (size_t)n * D_ * T_;

    cbn2s[tid] = cbn2g[tid];
    histl[tid] = 0u;
    if (tid < TB) ccnt[tid] = 0;
    if (tid == 0) qn = 0;

    f32x16 acc[4];
#pragma unroll
    for (int m = 0; m < 4; ++m)
#pragma unroll
        for (int r = 0; r < 16; ++r) acc[m][r] = 0.f;

    float xsq = 0.f;
    const float* xcol = x + xnb + t;

    for (int ks = 0; ks < 32; ++ks) {
        __syncthreads();                    // prior iter's slab reads done
        const short8* sg = cbf + ks * 2048; // 32KB contiguous slab
#pragma unroll
        for (int i = 0; i < 4; ++i) u.slab[i * 512 + tid] = sg[i * 512 + tid];
        // x column loads + hi/lo split (overlaps staging)
        const float* xp = xcol + (size_t)(ks * 16 + 8 * hh) * T_;
        short8 bh, bl;
#pragma unroll
        for (int j = 0; j < 8; ++j) {
            float v = xp[(size_t)j * T_];
            xsq = fmaf(v, v, xsq);
            unsigned short hb = f2bf(v);
            bh[j] = (short)hb;
            bl[j] = (short)f2bf(v - bf2f(hb));
        }
        __syncthreads();                    // slab ready
#pragma unroll
        for (int m = 0; m < 4; ++m) {
            short8 ah = u.slab[(0 * 16 + q * 4 + m) * 64 + l];
            short8 al = u.slab[(1 * 16 + q * 4 + m) * 64 + l];
            acc[m] = __builtin_amdgcn_mfma_f32_32x32x16_bf16(ah, bh, acc[m], 0, 0, 0);
            acc[m] = __builtin_amdgcn_mfma_f32_32x32x16_bf16(ah, bl, acc[m], 0, 0, 0);
            acc[m] = __builtin_amdgcn_mfma_f32_32x32x16_bf16(al, bh, acc[m], 0, 0, 0);
        }
    }
    __syncthreads();    // slab dead before ep-struct (union) writes

    // row norm: lane halves (hh=0/1) each summed half the d's for this t
    xsq += __shfl_xor(xsq, 32);
    float nrm = fmaxf(sqrtf(xsq), 1e-12f);
    float scl = 1.0f / nrm;
    float c1  = xsq * scl * scl;
    float n2s = -2.0f * scl;

    // per-lane argmin over its 64 codes (ties land in candidate set anyway)
    float bv = FLT_MAX; int bi = 0;
#pragma unroll
    for (int m = 0; m < 4; ++m) {
#pragma unroll
        for (int r = 0; r < 16; ++r) {
            int code = q * 128 + m * 32 + (r & 3) + 8 * (r >> 2) + 4 * hh;
            float dist = fmaf(n2s, acc[m][r], c1 + cbn2s[code]);
            if (dist < bv) { bv = dist; bi = code; }
        }
    }
    {   // combine lane halves (same t)
        float ov = __shfl_xor(bv, 32); int oi = __shfl_xor(bi, 32);
        if (ov < bv || (ov == bv && oi < bi)) { bv = ov; bi = oi; }
    }
    if (hh == 0) { u.ep.redv[q][tg * 32 + col] = bv; u.ep.redi[q][tg * 32 + col] = bi; }
    __syncthreads();
    if (tid < TB) {
        float mv = FLT_MAX; int mi = 0;
#pragma unroll
        for (int qq = 0; qq < 4; ++qq) {
            float v = u.ep.redv[qq][tid]; int ii = u.ep.redi[qq][tid];
            if (v < mv || (v == mv && ii < mi)) { mv = v; mi = ii; }
        }
        m1s[tid] = mv; sidx[tid] = mi;
    }
    __syncthreads();

    // near-tie candidates within DELTA of fp32 min
    {
        float thr = m1s[tg * 32 + col] + DELTA;
#pragma unroll
        for (int m = 0; m < 4; ++m) {
#pragma unroll
            for (int r = 0; r < 16; ++r) {
                int code = q * 128 + m * 32 + (r & 3) + 8 * (r >> 2) + 4 * hh;
                float dist = fmaf(n2s, acc[m][r], c1 + cbn2s[code]);
                if (dist <= thr) {
                    int p = atomicAdd(&ccnt[tg * 32 + col], 1);
                    if (p < 8) u.ep.cand[tg * 32 + col][p] = code;
                }
            }
        }
    }
    // commit loss = sum of min distances (wave 0 over the 64 t of this block)
    if (tid < 64) {
        float cl = m1s[tid];
#pragma unroll
        for (int o = 32; o; o >>= 1) cl += __shfl_down(cl, o);
        if (tid == 0) atomicAdd(closs, cl);
    }
    __syncthreads();
    if (tid < TB && ccnt[tid] > 1) { int p = atomicAdd(&qn, 1); u.ep.qrow[p] = tid; }
    __syncthreads();

    // wave-parallel fp64 refinement of ambiguous rows
    int nq = qn;
    for (int qi = w; qi < nq; qi += 8) {
        int row = u.ep.qrow[qi];
        const float* xr = x + xnb + t0 + row;
        float xv8[8]; double xs = 0.0;
#pragma unroll
        for (int k2 = 0; k2 < 8; ++k2) {
            float v = xr[(size_t)(l + 64 * k2) * T_];
            xv8[k2] = v; xs += (double)v * (double)v;
        }
#pragma unroll
        for (int o = 32; o; o >>= 1) xs += __shfl_xor(xs, o);
        if (xs < 1e-24) xs = 1e-24;
        double inv = 1.0 / sqrt(xs);
        double bd = 1e300; int bc = 1 << 30;
        int mm = ccnt[row] < 8 ? ccnt[row] : 8;
        for (int kk = 0; kk < mm; ++kk) {
            int c = u.ep.cand[row][kk];
            const float* cr = cb + (size_t)c * D_;
            double s2 = 0.0;
#pragma unroll
            for (int k2 = 0; k2 < 8; ++k2) {
                double df = (double)xv8[k2] * inv - (double)cr[l + 64 * k2];
                s2 += df * df;
            }
#pragma unroll
            for (int o = 32; o; o >>= 1) s2 += __shfl_xor(s2, o);
            if (s2 < bd || (s2 == bd && c < bc)) { bd = s2; bc = c; }
        }
        if (l == 0) sidx[row] = bc;
    }
    __syncthreads();

    if (tid < TB) atomicAdd(&histl[sidx[tid]], 1u);
    __syncthreads();
    if (histl[tid]) atomicAdd(&hist[tid], histl[tid]);

    // epilogue: gather chosen codebook rows via padded LDS transpose, float4 writes
    const int tt = tid >> 3, seg = tid & 7;
    for (int ds = 0; ds < 8; ++ds) {
        int dbase = ds * 64;
        __syncthreads();
        {
            int c = sidx[tt];
            const float4* src = (const float4*)(cb + (size_t)c * D_ + dbase + seg * 8);
            float4 v0 = src[0], v1 = src[1];
            int dd = seg * 8;
            u.ep.ot[dd + 0][tt] = v0.x; u.ep.ot[dd + 1][tt] = v0.y;
            u.ep.ot[dd + 2][tt] = v0.z; u.ep.ot[dd + 3][tt] = v0.w;
            u.ep.ot[dd + 4][tt] = v1.x; u.ep.ot[dd + 5][tt] = v1.y;
            u.ep.ot[dd + 6][tt] = v1.z; u.ep.ot[dd + 7][tt] = v1.w;
        }
        __syncthreads();
#pragma unroll
        for (int p = 0; p < 2; ++p) {
            int dd = p * 32 + (tid >> 4);
            float4 v = *(const float4*)&u.ep.ot[dd][(tid & 15) * 4];
            *(float4*)&out[xnb + (size_t)(dbase + dd) * T_ + t0 + (tid & 15) * 4] = v;
        }
    }

    // folded finalize: last block computes perplexity + commit-loss scalars
    __threadfence();
    if (tid == 0) {
        unsigned int tk = atomicAdd(ticket, 1u);
        lastf = (tk == (unsigned int)(GRID - 1));
    }
    __syncthreads();
    if (lastf) {
        unsigned int cnt = atomicAdd(&hist[tid], 0u);   // coherent read
        float p = (float)cnt * (1.0f / (float)NROW);
        float v = p * logf(p + 1e-7f);
#pragma unroll
        for (int o = 32; o; o >>= 1) v += __shfl_down(v, o);
        if (l == 0) psum[w] = v;
        __syncthreads();
        if (tid == 0) {
            float s = 0.f;
#pragma unroll
            for (int k = 0; k < 8; ++k) s += psum[k];
            float cls = atomicAdd(closs, 0.0f);
            out[OUT_ELEMS]     = cls * (1.0f / ((float)NROW * (float)D_));
            out[OUT_ELEMS + 1] = expf(-s);
        }
    }
}

extern "C" void kernel_launch(void* const* d_in, const int* in_sizes, int n_in,
                              void* d_out, int out_size, void* d_ws, size_t ws_size,
                              hipStream_t stream) {
    const float* x  = (const float*)d_in[0];
    const float* cb = (const float*)d_in[1];
    float* out = (float*)d_out;
    float* ws  = (float*)d_ws;
    float* closs         = ws;                          // [0]
    unsigned int* ticket = (unsigned int*)(ws + 1);     // [1]
    unsigned int* hist   = (unsigned int*)(ws + 16);    // [16..527]
    float* cbn2          = ws + 528;                    // [528..1039]
    short8* cbf          = (short8*)(ws + 1040);        // 1 MB

    prep_k<<<64, 512, 0, stream>>>(cb, cbn2, cbf, (unsigned int*)ws);
    vq_main<<<GRID, THREADS, 0, stream>>>(x, cb, out, closs, hist, cbn2, cbf, ticket);
}

// Round 6
// 496.912 us; speedup vs baseline: 1.2634x; 1.2634x over previous
//
#include <hip/hip_runtime.h>
#include <cstdint>
#include <cfloat>

#define N_   32
#define D_   512
#define T_   2048
#define NC   512
#define NROW (N_ * T_)           // 65536 rows
#define OUT_ELEMS (N_ * D_ * T_) // 33554432
#define TB   128                 // t columns per block
#define THREADS 512
#define GRID 512
#define DELTA 2e-4f

typedef __attribute__((ext_vector_type(8)))  short short8;
typedef __attribute__((ext_vector_type(16))) float f32x16;

// ws layout (4B units): [0] closs | [1] ticket | [16..527] hist | [528..1039] cbn2
// | byte 4160: cbf short8[65536] (1MB), layout [ks(32)][h(2)][ct(16)][l(64)]

__device__ inline unsigned short f2bf(float x) {
    unsigned int u = __float_as_uint(x);
    return (unsigned short)((u + 0x7fffu + ((u >> 16) & 1u)) >> 16);
}
__device__ inline float bf2f(unsigned short b) {
    return __uint_as_float(((unsigned int)b) << 16);
}

// merged: zero ws header + codebook norms + MFMA fragment build (hi/lo bf16)
__global__ __launch_bounds__(512) void prep_k(const float* __restrict__ cb,
                                              float* __restrict__ cbn2,
                                              short8* __restrict__ cbf,
                                              unsigned int* __restrict__ wsz) {
    const int tid = threadIdx.x, bid = blockIdx.x;
    if (bid == 0) {
        wsz[tid] = 0u;                      // 0..511
        if (tid < 16) wsz[512 + tid] = 0u;  // 512..527
    }
    {
        int w = tid >> 6, l = tid & 63;
        int c = bid * 8 + w;
        const float* row = cb + (size_t)c * D_;
        float s = 0.f;
#pragma unroll
        for (int j = 0; j < 8; ++j) { float v = row[l * 8 + j]; s = fmaf(v, v, s); }
#pragma unroll
        for (int o = 32; o; o >>= 1) s += __shfl_down(s, o);
        if (l == 0) cbn2[c] = s;
    }
    // fragments for 32x32x16: lane fl holds A[row=fl&31][k=8*(fl>>5)+j]
    {
        int gid = bid * 512 + tid;               // 0..32767
        int ks = gid >> 10, ct = (gid >> 6) & 15, fl = gid & 63;
        const float* src = cb + (size_t)(ct * 32 + (fl & 31)) * D_ + ks * 16 + 8 * (fl >> 5);
        short8 h, lo;
#pragma unroll
        for (int j = 0; j < 8; ++j) {
            float v = src[j];
            unsigned short hb = f2bf(v);
            h[j]  = (short)hb;
            lo[j] = (short)f2bf(v - bf2f(hb));
        }
        cbf[((ks * 2 + 0) * 16 + ct) * 64 + fl] = h;
        cbf[((ks * 2 + 1) * 16 + ct) * 64 + fl] = lo;
    }
}

__global__ __launch_bounds__(THREADS, 2) void vq_main(
    const float* __restrict__ x, const float* __restrict__ cb,
    float* __restrict__ out, float* __restrict__ closs,
    unsigned int* __restrict__ hist, const float* __restrict__ cbn2g,
    const short8* __restrict__ cbf, unsigned int* __restrict__ ticket) {

    __shared__ union U {
        short8 slab[2][2048];               // 2 x 32KB double buffer
        struct {
            float ot[64][TB + 4];           // epilogue transpose
            float redv[2][TB];
            int   redi[2][TB];
            int   cand[TB][8];
            int   qrow[TB];
        } ep;
    } u;
    __shared__ float cbn2s[NC];
    __shared__ float m1s[TB];
    __shared__ int   sidx[TB], ccnt[TB];
    __shared__ int   qn, lastf;
    __shared__ unsigned int histl[NC];
    __shared__ float psum[8];

    const int tid = threadIdx.x, l = tid & 63, w = tid >> 6;
    const int q = w & 1, tg = w >> 1;       // code-half, t-group
    const int col = l & 31, hh = l >> 5;    // t-in-group, k/row-half
    const int bid = blockIdx.x;
    const int n = bid >> 4, t0 = (bid & 15) * TB;
    const int t = t0 + tg * 32 + col;
    const size_t xnb = (size_t)n * D_ * T_;

    cbn2s[tid] = cbn2g[tid];
    histl[tid] = 0u;
    if (tid < TB) ccnt[tid] = 0;
    if (tid == 0) qn = 0;

    f32x16 acc[8];
#pragma unroll
    for (int m = 0; m < 8; ++m)
#pragma unroll
        for (int r = 0; r < 16; ++r) acc[m][r] = 0.f;

    float xsq = 0.f;
    const float* xcol = x + xnb + t;

    // prologue: x[0] to regs, slab[0] to LDS buf0
    float gx[8];
    {
        const float* xp = xcol + (size_t)(8 * hh) * T_;
#pragma unroll
        for (int j = 0; j < 8; ++j) gx[j] = xp[(size_t)j * T_];
        const short8* sg = cbf;
#pragma unroll
        for (int i = 0; i < 4; ++i) u.slab[0][i * 512 + tid] = sg[i * 512 + tid];
    }
    __syncthreads();

    for (int ks = 0; ks < 32; ++ks) {
        const int cur = ks & 1, nxt = cur ^ 1;
        const int ksn = (ks + 1) & 31;
        // pack B fragments from prefetched regs
        short8 bh, bl;
#pragma unroll
        for (int j = 0; j < 8; ++j) {
            float v = gx[j];
            xsq = fmaf(v, v, xsq);
            unsigned short hb = f2bf(v);
            bh[j] = (short)hb;
            bl[j] = (short)f2bf(v - bf2f(hb));
        }
        // issue prefetches for ks+1 (x -> regs, slab -> sreg), consumed later
        {
            const float* xp = xcol + (size_t)(ksn * 16 + 8 * hh) * T_;
#pragma unroll
            for (int j = 0; j < 8; ++j) gx[j] = xp[(size_t)j * T_];
        }
        short8 sreg[4];
        {
            const short8* sg = cbf + ksn * 2048;
#pragma unroll
            for (int i = 0; i < 4; ++i) sreg[i] = sg[i * 512 + tid];
        }
        // MFMA phase over current slab (hides the prefetch latency)
#pragma unroll
        for (int m = 0; m < 8; ++m) {
            short8 ah = u.slab[cur][(0 * 16 + q * 8 + m) * 64 + l];
            short8 al = u.slab[cur][(1 * 16 + q * 8 + m) * 64 + l];
            acc[m] = __builtin_amdgcn_mfma_f32_32x32x16_bf16(ah, bh, acc[m], 0, 0, 0);
            acc[m] = __builtin_amdgcn_mfma_f32_32x32x16_bf16(ah, bl, acc[m], 0, 0, 0);
            acc[m] = __builtin_amdgcn_mfma_f32_32x32x16_bf16(al, bh, acc[m], 0, 0, 0);
        }
        // write staged slab for ks+1
#pragma unroll
        for (int i = 0; i < 4; ++i) u.slab[nxt][i * 512 + tid] = sreg[i];
        __syncthreads();
    }
    __syncthreads();    // slab dead before ep-union writes

    // row norm across lane halves (same t)
    xsq += __shfl_xor(xsq, 32);
    float nrm = fmaxf(sqrtf(xsq), 1e-12f);
    float scl = 1.0f / nrm;
    float c1  = xsq * scl * scl;
    float n2s = -2.0f * scl;

    // per-lane argmin over its 128 codes
    float bv = FLT_MAX; int bi = 0;
#pragma unroll
    for (int m = 0; m < 8; ++m) {
#pragma unroll
        for (int r = 0; r < 16; ++r) {
            int code = q * 256 + m * 32 + (r & 3) + 8 * (r >> 2) + 4 * hh;
            float dist = fmaf(n2s, acc[m][r], c1 + cbn2s[code]);
            if (dist < bv) { bv = dist; bi = code; }
        }
    }
    {   // combine lane halves (same t); q=0 half has lower codes -> tiebreak ok
        float ov = __shfl_xor(bv, 32); int oi = __shfl_xor(bi, 32);
        if (ov < bv || (ov == bv && oi < bi)) { bv = ov; bi = oi; }
    }
    if (hh == 0) { u.ep.redv[q][tg * 32 + col] = bv; u.ep.redi[q][tg * 32 + col] = bi; }
    __syncthreads();
    if (tid < TB) {
        float mv = u.ep.redv[0][tid]; int mi = u.ep.redi[0][tid];
        float v1 = u.ep.redv[1][tid]; int i1 = u.ep.redi[1][tid];
        if (v1 < mv || (v1 == mv && i1 < mi)) { mv = v1; mi = i1; }
        m1s[tid] = mv; sidx[tid] = mi;
    }
    __syncthreads();

    // near-tie candidates within DELTA of fp32 min
    {
        float thr = m1s[tg * 32 + col] + DELTA;
#pragma unroll
        for (int m = 0; m < 8; ++m) {
#pragma unroll
            for (int r = 0; r < 16; ++r) {
                int code = q * 256 + m * 32 + (r & 3) + 8 * (r >> 2) + 4 * hh;
                float dist = fmaf(n2s, acc[m][r], c1 + cbn2s[code]);
                if (dist <= thr) {
                    int p = atomicAdd(&ccnt[tg * 32 + col], 1);
                    if (p < 8) u.ep.cand[tg * 32 + col][p] = code;
                }
            }
        }
    }
    // commit loss = sum of min distances (waves 0..1 cover 128 t)
    if (tid < TB) {
        float cl = m1s[tid];
#pragma unroll
        for (int o = 32; o; o >>= 1) cl += __shfl_down(cl, o);
        if (l == 0) atomicAdd(closs, cl);
    }
    __syncthreads();
    if (tid < TB && ccnt[tid] > 1) { int p = atomicAdd(&qn, 1); u.ep.qrow[p] = tid; }
    __syncthreads();

    // wave-parallel fp64 refinement of ambiguous rows
    int nq = qn;
    for (int qi = w; qi < nq; qi += 8) {
        int row = u.ep.qrow[qi];
        const float* xr = x + xnb + t0 + row;
        float xv8[8]; double xs = 0.0;
#pragma unroll
        for (int k2 = 0; k2 < 8; ++k2) {
            float v = xr[(size_t)(l + 64 * k2) * T_];
            xv8[k2] = v; xs += (double)v * (double)v;
        }
#pragma unroll
        for (int o = 32; o; o >>= 1) xs += __shfl_xor(xs, o);
        if (xs < 1e-24) xs = 1e-24;
        double inv = 1.0 / sqrt(xs);
        double bd = 1e300; int bc = 1 << 30;
        int mm = ccnt[row] < 8 ? ccnt[row] : 8;
        for (int kk = 0; kk < mm; ++kk) {
            int c = u.ep.cand[row][kk];
            const float* cr = cb + (size_t)c * D_;
            double s2 = 0.0;
#pragma unroll
            for (int k2 = 0; k2 < 8; ++k2) {
                double df = (double)xv8[k2] * inv - (double)cr[l + 64 * k2];
                s2 += df * df;
            }
#pragma unroll
            for (int o = 32; o; o >>= 1) s2 += __shfl_xor(s2, o);
            if (s2 < bd || (s2 == bd && c < bc)) { bd = s2; bc = c; }
        }
        if (l == 0) sidx[row] = bc;
    }
    __syncthreads();

    if (tid < TB) atomicAdd(&histl[sidx[tid]], 1u);
    __syncthreads();
    if (histl[tid]) atomicAdd(&hist[tid], histl[tid]);

    // epilogue: gather chosen codebook rows via padded LDS transpose, float4 writes
    const int tt = tid >> 2, seg = tid & 3;
    for (int ds = 0; ds < 8; ++ds) {
        int dbase = ds * 64;
        __syncthreads();
        {
            int c = sidx[tt];
            const float4* src = (const float4*)(cb + (size_t)c * D_ + dbase + seg * 16);
#pragma unroll
            for (int qq = 0; qq < 4; ++qq) {
                float4 v = src[qq];
                int dd = seg * 16 + qq * 4;
                u.ep.ot[dd + 0][tt] = v.x; u.ep.ot[dd + 1][tt] = v.y;
                u.ep.ot[dd + 2][tt] = v.z; u.ep.ot[dd + 3][tt] = v.w;
            }
        }
        __syncthreads();
#pragma unroll
        for (int p = 0; p < 4; ++p) {
            int dd = p * 16 + (tid >> 5);
            float4 v = *(const float4*)&u.ep.ot[dd][(tid & 31) * 4];
            *(float4*)&out[xnb + (size_t)(dbase + dd) * T_ + t0 + (tid & 31) * 4] = v;
        }
    }

    // folded finalize: last block computes perplexity + commit-loss scalars
    __threadfence();
    if (tid == 0) {
        unsigned int tk = atomicAdd(ticket, 1u);
        lastf = (tk == (unsigned int)(GRID - 1));
    }
    __syncthreads();
    if (lastf) {
        unsigned int cnt = atomicAdd(&hist[tid], 0u);   // coherent read
        float p = (float)cnt * (1.0f / (float)NROW);
        float v = p * logf(p + 1e-7f);
#pragma unroll
        for (int o = 32; o; o >>= 1) v += __shfl_down(v, o);
        if (l == 0) psum[w] = v;
        __syncthreads();
        if (tid == 0) {
            float s = 0.f;
#pragma unroll
            for (int k = 0; k < 8; ++k) s += psum[k];
            float cls = atomicAdd(closs, 0.0f);
            out[OUT_ELEMS]     = cls * (1.0f / ((float)NROW * (float)D_));
            out[OUT_ELEMS + 1] = expf(-s);
        }
    }
}

extern "C" void kernel_launch(void* const* d_in, const int* in_sizes, int n_in,
                              void* d_out, int out_size, void* d_ws, size_t ws_size,
                              hipStream_t stream) {
    const float* x  = (const float*)d_in[0];
    const float* cb = (const float*)d_in[1];
    float* out = (float*)d_out;
    float* ws  = (float*)d_ws;
    float* closs         = ws;                          // [0]
    unsigned int* ticket = (unsigned int*)(ws + 1);     // [1]
    unsigned int* hist   = (unsigned int*)(ws + 16);    // [16..527]
    float* cbn2          = ws + 528;                    // [528..1039]
    short8* cbf          = (short8*)(ws + 1040);        // 1 MB

    prep_k<<<64, 512, 0, stream>>>(cb, cbn2, cbf, (unsigned int*)ws);
    vq_main<<<GRID, THREADS, 0, stream>>>(x, cb, out, closs, hist, cbn2, cbf, ticket);
}